// Round 19
// baseline (45.690 us; speedup 1.0000x reference)
//
#include <hip/hip_runtime.h>
#include <math.h>

#define HID 64

typedef __attribute__((ext_vector_type(4))) float f32x4;
typedef __attribute__((ext_vector_type(8))) __bf16 bf16x8;
typedef __attribute__((ext_vector_type(4))) __bf16 bf16x4;

__device__ __forceinline__ float fast_tanh(float x) {
    // tanh(x) = 1 - 2/(exp(2x)+1); exp overflow -> inf -> rcp -> 0 -> 1 (correct)
    float e = __expf(2.0f * x);
    return 1.0f - 2.0f * __builtin_amdgcn_rcpf(e + 1.0f);
}

// ---- prep: bf16 weight tables (W2, W2^T) + E_des, all into d_ws ----
__global__ void prep_kernel(const float* __restrict__ W1, const float* __restrict__ b1,
                            const float* __restrict__ W2, const float* __restrict__ b2,
                            const float* __restrict__ W3, const float* __restrict__ b3,
                            const float* __restrict__ x0, float* __restrict__ edes_out,
                            __bf16* __restrict__ W2bf, __bf16* __restrict__ W2Tbf) {
    int tid = threadIdx.x;  // 256 threads
    for (int idx = tid; idx < HID * HID; idx += 256) {
        W2bf[idx] = (__bf16)W2[idx];
        int r = idx >> 6, c = idx & 63;
        W2Tbf[idx] = (__bf16)W2[c * HID + r];
    }
    if (tid < 64) {
        int j = tid;
        float q1 = x0[0], q2 = x0[1], p1 = x0[2], p2 = x0[3];
        float h1j = fast_tanh(fmaf(q1, W1[j], fmaf(q2, W1[HID + j], b1[j])));
        float z = b2[j];
#pragma unroll 1
        for (int i = 0; i < HID; i++) {
            float hi = __shfl(h1j, i, 64);
            z = fmaf(hi, W2[i * HID + j], z);
        }
        float h2 = fast_tanh(z);
        float v = h2 * W3[j];
#pragma unroll
        for (int off = 32; off; off >>= 1) v += __shfl_xor(v, off, 64);
        if (j == 0) {
            float V = v + b3[0];
            float s, c;
            __sincosf(q2, &s, &c);
            float DEN = 2.0f - c * c;
            float rDEN = __builtin_amdgcn_rcpf(DEN);
            float quad = (p1 * p1 - 2.0f * (c + 1.0f) * p1 * p2 + (2.0f * c + 3.0f) * p2 * p2) * rDEN;
            float kin = 0.5f * quad;
            float s1, c1;
            __sincosf(q1, &s1, &c1);
            float c12 = c1 * c - s1 * s;
            float dq = 1.57079632679489662f - q2;
            float pot = -9.81f * (c12 + 2.0f * c1) + 0.5f * dq * dq;
            edes_out[0] = pot + kin + V;
        }
    }
}

// 8 tanh into fragment F + mask fragment M (wa0..bb1 in scope)
#define TANH8M(F, M, Q1v, Q2v)                                                                        \
    {                                                                                                 \
        float h;                                                                                      \
        h = fast_tanh(fmaf(Q1v, wa0.x, fmaf(Q2v, wb0.x, bb0.x))); F[0] = (__bf16)h; M[0] = (__bf16)fmaf(-h, h, 1.0f); \
        h = fast_tanh(fmaf(Q1v, wa0.y, fmaf(Q2v, wb0.y, bb0.y))); F[1] = (__bf16)h; M[1] = (__bf16)fmaf(-h, h, 1.0f); \
        h = fast_tanh(fmaf(Q1v, wa0.z, fmaf(Q2v, wb0.z, bb0.z))); F[2] = (__bf16)h; M[2] = (__bf16)fmaf(-h, h, 1.0f); \
        h = fast_tanh(fmaf(Q1v, wa0.w, fmaf(Q2v, wb0.w, bb0.w))); F[3] = (__bf16)h; M[3] = (__bf16)fmaf(-h, h, 1.0f); \
        h = fast_tanh(fmaf(Q1v, wa1.x, fmaf(Q2v, wb1.x, bb1.x))); F[4] = (__bf16)h; M[4] = (__bf16)fmaf(-h, h, 1.0f); \
        h = fast_tanh(fmaf(Q1v, wa1.y, fmaf(Q2v, wb1.y, bb1.y))); F[5] = (__bf16)h; M[5] = (__bf16)fmaf(-h, h, 1.0f); \
        h = fast_tanh(fmaf(Q1v, wa1.z, fmaf(Q2v, wb1.z, bb1.z))); F[6] = (__bf16)h; M[6] = (__bf16)fmaf(-h, h, 1.0f); \
        h = fast_tanh(fmaf(Q1v, wa1.w, fmaf(Q2v, wb1.w, bb1.w))); F[7] = (__bf16)h; M[7] = (__bf16)fmaf(-h, h, 1.0f); \
    }

// layer-1 half fragment + mask store for all 3 tiles; one set of weight loads
#define L1HALF3(FA, FB, FC, K0)                                             \
    do {                                                                    \
        const float4 wa0 = *(const float4*)(W1 + (K0));                     \
        const float4 wa1 = *(const float4*)(W1 + (K0) + 4);                 \
        const float4 wb0 = *(const float4*)(W1 + HID + (K0));               \
        const float4 wb1 = *(const float4*)(W1 + HID + (K0) + 4);           \
        const float4 bb0 = *(const float4*)(b1 + (K0));                     \
        const float4 bb1 = *(const float4*)(b1 + (K0) + 4);                 \
        bf16x8 mA, mB, mC;                                                  \
        TANH8M(FA, mA, q1A, q2A)                                            \
        TANH8M(FB, mB, q1B, q2B)                                            \
        TANH8M(FC, mC, q1C, q2C)                                            \
        const int mo = rowbase + ((K0) ^ swz);                              \
        *(bf16x8*)(mkA + mo) = mA;                                          \
        *(bf16x8*)(mkB + mo) = mB;                                          \
        *(bf16x8*)(mkC + mo) = mC;                                          \
    } while (0)

#define MFMA __builtin_amdgcn_mfma_f32_16x16x32_bf16

// tanh + V partial + g2 pack/store, one tile (w3v in scope)
#define H2ONE(Z, VP, GBUF, MT)                                                      \
    do {                                                                            \
        float h, g0_, g1_, g2_, g3_;                                                \
        h = fast_tanh(Z[0]); VP = fmaf(h, w3v.x, VP); g0_ = w3v.x * (1.0f - h * h); \
        h = fast_tanh(Z[1]); VP = fmaf(h, w3v.y, VP); g1_ = w3v.y * (1.0f - h * h); \
        h = fast_tanh(Z[2]); VP = fmaf(h, w3v.z, VP); g2_ = w3v.z * (1.0f - h * h); \
        h = fast_tanh(Z[3]); VP = fmaf(h, w3v.w, VP); g3_ = w3v.w * (1.0f - h * h); \
        bf16x4 gv = {(__bf16)g0_, (__bf16)g1_, (__bf16)g2_, (__bf16)g3_};           \
        *(bf16x4*)((GBUF) + rowbase + ((16 * (MT) + 4 * hi) ^ swz)) = gv;           \
    } while (0)

// one forward m-tile: bias init + GEMM1 + tanh/V/g2 for all 3 tiles; accs die here
#define FWDMT(MT)                                                           \
    do {                                                                    \
        const float4 b2v = *(const float4*)(b2 + 16 * (MT) + 4 * hi);       \
        f32x4 zA = {b2v.x, b2v.y, b2v.z, b2v.w};                            \
        f32x4 zB = zA, zC = zA;                                             \
        const bf16x8 wf0 = *(const bf16x8*)(w2t + (MT) * 1024);             \
        zA = MFMA(wf0, a10A, zA, 0, 0, 0);                                  \
        zB = MFMA(wf0, a10B, zB, 0, 0, 0);                                  \
        zC = MFMA(wf0, a10C, zC, 0, 0, 0);                                  \
        const bf16x8 wf1 = *(const bf16x8*)(w2t + (MT) * 1024 + 32);        \
        zA = MFMA(wf1, a11A, zA, 0, 0, 0);                                  \
        zB = MFMA(wf1, a11B, zB, 0, 0, 0);                                  \
        zC = MFMA(wf1, a11C, zC, 0, 0, 0);                                  \
        const float4 w3v = *(const float4*)(W3 + 16 * (MT) + 4 * hi);       \
        H2ONE(zA, vpA, g2A, MT);                                            \
        H2ONE(zB, vpB, g2B, MT);                                            \
        H2ONE(zC, vpC, g2C, MT);                                            \
    } while (0)

// backward one tile at m-tile MT: mask loaded from LDS (no tanh recompute)
#define DVONE(R, MK, MT, D1, D2)                                                              \
    do {                                                                                      \
        const bf16x4 mv = *(const bf16x4*)((MK) + rowbase + ((16 * (MT) + 4 * hi) ^ swz));    \
        float gi;                                                                             \
        gi = (float)mv[0] * R[0]; D1 = fmaf(w1av.x, gi, D1); D2 = fmaf(w1bv.x, gi, D2);       \
        gi = (float)mv[1] * R[1]; D1 = fmaf(w1av.y, gi, D1); D2 = fmaf(w1bv.y, gi, D2);       \
        gi = (float)mv[2] * R[2]; D1 = fmaf(w1av.z, gi, D1); D2 = fmaf(w1bv.z, gi, D2);       \
        gi = (float)mv[3] * R[3]; D1 = fmaf(w1av.w, gi, D1); D2 = fmaf(w1bv.w, gi, D2);       \
    } while (0)

// one backward m-tile: GEMM2 + mask/dV for all 3 tiles; accs die here
#define BWDMT(MT)                                                           \
    do {                                                                    \
        f32x4 rA = {0.f, 0.f, 0.f, 0.f};                                    \
        f32x4 rB = rA, rC = rA;                                             \
        const bf16x8 wf0 = *(const bf16x8*)(w2b + (MT) * 1024);             \
        rA = MFMA(wf0, a20A, rA, 0, 0, 0);                                  \
        rB = MFMA(wf0, a20B, rB, 0, 0, 0);                                  \
        rC = MFMA(wf0, a20C, rC, 0, 0, 0);                                  \
        const bf16x8 wf1 = *(const bf16x8*)(w2b + (MT) * 1024 + 32);        \
        rA = MFMA(wf1, a21A, rA, 0, 0, 0);                                  \
        rB = MFMA(wf1, a21B, rB, 0, 0, 0);                                  \
        rC = MFMA(wf1, a21C, rC, 0, 0, 0);                                  \
        const float4 w1av = *(const float4*)(W1 + 16 * (MT) + 4 * hi);      \
        const float4 w1bv = *(const float4*)(W1 + HID + 16 * (MT) + 4 * hi);\
        DVONE(rA, mkA, MT, d1A, d2A);                                       \
        DVONE(rB, mkB, MT, d1B, d2B);                                       \
        DVONE(rC, mkC, MT, d1C, d2C);                                       \
    } while (0)

#define RED2(V) V += __shfl_xor(V, 16, 64); V += __shfl_xor(V, 32, 64);

#define SEL3(A, B, C) ((hi == 0) ? (A) : (hi == 1) ? (B) : (C))

// ---- main: THREE interleaved 16-row tiles per wave; 12 KB LDS/wave -> 3 blocks/CU ----
__global__ __launch_bounds__(256, 3) void pend_kernel(
    const float4* __restrict__ x,
    const float* __restrict__ W1, const float* __restrict__ b1,
    const __bf16* __restrict__ W2bf, const __bf16* __restrict__ W2Tbf,
    const float* __restrict__ b2,
    const float* __restrict__ W3, const float* __restrict__ b3,
    const float* __restrict__ Tp, const float* __restrict__ edes_p,
    float4* __restrict__ out, int n)
{
    __shared__ __align__(16) __bf16 lds[4 * 6144];  // per wave: g2 x3 (2KB) + mask x3 (2KB)
    const int tid = threadIdx.x;
    const int w = tid >> 6, l = tid & 63;
    const int lo = l & 15, hi = l >> 4;
    __bf16* g2A = lds + w * 6144;
    __bf16* g2B = g2A + 1024;
    __bf16* g2C = g2B + 1024;
    __bf16* mkA = g2C + 1024;
    __bf16* mkB = mkA + 1024;
    __bf16* mkC = mkB + 1024;

    const float E_des = edes_p[0];
    const float Tabs = fabsf(Tp[0]);
    const float b3c = b3[0];

    const int base = blockIdx.x * 192 + w * 48;   // 48 rows per wave
    int eA = base + lo;       if (eA >= n) eA = n - 1;
    int eB = base + 16 + lo;  if (eB >= n) eB = n - 1;
    int eC = base + 32 + lo;  if (eC >= n) eC = n - 1;
    const float4 xvA = x[eA];
    const float4 xvB = x[eB];
    const float4 xvC = x[eC];
    const float q1A = xvA.x, q2A = xvA.y, p1A = xvA.z, p2A = xvA.w;
    const float q1B = xvB.x, q2B = xvB.y, p1B = xvB.z, p2B = xvB.w;
    const float q1C = xvC.x, q2C = xvC.y, p1C = xvC.z, p2C = xvC.w;

    const int swz = (lo & 7) << 3;          // XOR swizzle on j (bits 3..5)
    const int rowbase = lo * HID;

    // ---- layer-1 for 3 tiles (shared weight loads); masks stored to LDS ----
    bf16x8 a10A, a11A, a10B, a11B, a10C, a11C;
    L1HALF3(a10A, a10B, a10C, 8 * hi);
    L1HALF3(a11A, a11B, a11C, 32 + 8 * hi);

    const __bf16* w2t = W2Tbf + lo * HID + 8 * hi;   // + mt*1024 (+32 for kh=1)
    const __bf16* w2b = W2bf  + lo * HID + 8 * hi;

    // ---- forward: GEMM1 + h2/V/g2, one m-tile at a time (short acc lifetimes) ----
    float vpA = 0.0f, vpB = 0.0f, vpC = 0.0f;
    FWDMT(0);
    FWDMT(1);
    FWDMT(2);
    FWDMT(3);

    // ---- GEMM2 A-fragments from LDS (all g2 writes precede these reads, same wave) ----
    const bf16x8 a20A = *(const bf16x8*)(g2A + rowbase + ((8 * hi) ^ swz));
    const bf16x8 a21A = *(const bf16x8*)(g2A + rowbase + ((32 + 8 * hi) ^ swz));
    const bf16x8 a20B = *(const bf16x8*)(g2B + rowbase + ((8 * hi) ^ swz));
    const bf16x8 a21B = *(const bf16x8*)(g2B + rowbase + ((32 + 8 * hi) ^ swz));
    const bf16x8 a20C = *(const bf16x8*)(g2C + rowbase + ((8 * hi) ^ swz));
    const bf16x8 a21C = *(const bf16x8*)(g2C + rowbase + ((32 + 8 * hi) ^ swz));

    // ---- backward: GEMM2 + mask/dV, one m-tile at a time ----
    float d1A = 0.f, d2A = 0.f, d1B = 0.f, d2B = 0.f, d1C = 0.f, d2C = 0.f;
    BWDMT(0);
    BWDMT(1);
    BWDMT(2);
    BWDMT(3);

    // ---- reduce over hi-groups; lanes l<48 then own row base + l (tile = hi) ----
    RED2(vpA) RED2(vpB) RED2(vpC)
    RED2(d1A) RED2(d1B) RED2(d1C)
    RED2(d2A) RED2(d2B) RED2(d2C)

    const float V    = SEL3(vpA, vpB, vpC) + b3c;
    const float dVq1 = SEL3(d1A, d1B, d1C);
    const float dVq2 = SEL3(d2A, d2B, d2C);
    const float q1 = SEL3(q1A, q1B, q1C);
    const float q2 = SEL3(q2A, q2B, q2C);
    const float p1 = SEL3(p1A, p1B, p1C);
    const float p2 = SEL3(p2A, p2B, p2C);

    // ---- physics, once per lane (row = base + l; hi==3 lanes redundant, no store) ----
    float s2q, c2q, s1q, c1q;
    __sincosf(q2, &s2q, &c2q);
    __sincosf(q1, &s1q, &c1q);
    const float s12 = s1q * c2q + c1q * s2q;
    const float c12 = c1q * c2q - s1q * s2q;

    const float cc = c2q, s = s2q;
    const float DEN = 2.0f - cc * cc;        // == 1 + s^2
    const float rDEN = __builtin_amdgcn_rcpf(DEN);
    const float cp1 = cc + 1.0f;

    const float quad = (p1 * p1 - 2.0f * cp1 * p1 * p2 + (2.0f * cc + 3.0f) * p2 * p2) * rDEN;
    const float kin = 0.5f * quad;
    const float dqa = 1.57079632679489662f - q2;
    const float pot = -9.81f * (c12 + 2.0f * c1q) + 0.5f * dqa * dqa;
    const float E = pot + kin + V;

    const float fac = (quad > 0.0f) ? __builtin_amdgcn_rsqf(quad) : 1.0f;
    const float coef = E_des - E;
    const float u1 = -dVq1 + coef * p1 * fac;
    const float u2 = -dVq2 + coef * p2 * fac;

    const float dq1dt = (p1 - cp1 * p2) * rDEN;
    const float dq2dt = ((2.0f * cc + 3.0f) * p2 - cp1 * p1) * rDEN;
    const float dp1dt = -9.81f * (s12 + 2.0f * s1q) + u1;

    const float inner = -p2 * p2 * s * cp1 * (cc + 2.0f)
                + p1 * p2 * s * (fmaf(cc, cc, fmaf(2.0f, cc, 2.0f)))
                - cc * p1 * p1 * s
                + DEN * DEN * (fmaf(9.81f, s12, -0.5f * (3.14159265358979324f - 2.0f * q2)));
    const float dp2dt = -(inner * rDEN * rDEN) + u2;

    const int row = base + l;
    if (l < 48 && row < n) {
        float4 o;
        o.x = Tabs * dq1dt;
        o.y = Tabs * dq2dt;
        o.z = Tabs * dp1dt;
        o.w = Tabs * dp2dt;
        out[row] = o;
    }
}

extern "C" void kernel_launch(void* const* d_in, const int* in_sizes, int n_in,
                              void* d_out, int out_size, void* d_ws, size_t ws_size,
                              hipStream_t stream) {
    const float* x  = (const float*)d_in[0];
    // d_in[1] = t (unused)
    const float* W1 = (const float*)d_in[2];
    const float* b1 = (const float*)d_in[3];
    const float* W2 = (const float*)d_in[4];
    const float* b2 = (const float*)d_in[5];
    const float* W3 = (const float*)d_in[6];
    const float* b3 = (const float*)d_in[7];
    const float* Tp = (const float*)d_in[8];
    const float* x0 = (const float*)d_in[9];

    float* ws = (float*)d_ws;
    float* edes = ws;                                   // 1 float (+ padding to 64B)
    __bf16* W2bf  = (__bf16*)(ws + 16);                 // 4096 bf16 = 8 KB
    __bf16* W2Tbf = W2bf + HID * HID;                   // 4096 bf16 = 8 KB

    prep_kernel<<<1, 256, 0, stream>>>(W1, b1, W2, b2, W3, b3, x0, edes, W2bf, W2Tbf);

    int n = in_sizes[0] / 4;  // 500000
    int blocks = (n + 191) / 192;  // 192 rows per block (4 waves x 3 tiles x 16) -> 2605
    pend_kernel<<<blocks, 256, 0, stream>>>((const float4*)x, W1, b1, W2bf, W2Tbf,
                                            b2, W3, b3, Tp, edes, (float4*)d_out, n);
}

// Round 20
// 42.569 us; speedup vs baseline: 1.0733x; 1.0733x over previous
//
#include <hip/hip_runtime.h>
#include <math.h>

#define HID 64

typedef __attribute__((ext_vector_type(4))) float f32x4;
typedef __attribute__((ext_vector_type(8))) __bf16 bf16x8;
typedef __attribute__((ext_vector_type(4))) __bf16 bf16x4;

__device__ __forceinline__ float fast_tanh(float x) {
    // tanh(x) = 1 - 2/(exp(2x)+1)
    float e = __expf(2.0f * x);
    return 1.0f - 2.0f * __builtin_amdgcn_rcpf(e + 1.0f);
}

// argument pre-scaled by K = 2*log2(e): tanh(x) = 1 - 2/(2^(K x) + 1)
__device__ __forceinline__ float fast_tanh2(float zs) {
    float e = __builtin_amdgcn_exp2f(zs);
    return 1.0f - 2.0f * __builtin_amdgcn_rcpf(e + 1.0f);
}

#define KSCALE 2.885390081777926815f   // 2*log2(e)

// ---- prep: bf16 weight tables (W2, K*W2^T) + scaled W1/b1/b2 + E_des into d_ws ----
__global__ void prep_kernel(const float* __restrict__ W1, const float* __restrict__ b1,
                            const float* __restrict__ W2, const float* __restrict__ b2,
                            const float* __restrict__ W3, const float* __restrict__ b3,
                            const float* __restrict__ x0, float* __restrict__ edes_out,
                            __bf16* __restrict__ W2bf, __bf16* __restrict__ W2Tbf,
                            float* __restrict__ W1s, float* __restrict__ b1s,
                            float* __restrict__ b2s) {
    int tid = threadIdx.x;  // 256 threads
    for (int idx = tid; idx < HID * HID; idx += 256) {
        W2bf[idx] = (__bf16)W2[idx];
        int r = idx >> 6, c = idx & 63;
        W2Tbf[idx] = (__bf16)(KSCALE * W2[c * HID + r]);
    }
    if (tid < 2 * HID) W1s[tid] = KSCALE * W1[tid];
    if (tid < HID) { b1s[tid] = KSCALE * b1[tid]; b2s[tid] = KSCALE * b2[tid]; }
    if (tid < 64) {
        int j = tid;
        float q1 = x0[0], q2 = x0[1], p1 = x0[2], p2 = x0[3];
        float h1j = fast_tanh(fmaf(q1, W1[j], fmaf(q2, W1[HID + j], b1[j])));
        float z = b2[j];
#pragma unroll 1
        for (int i = 0; i < HID; i++) {
            float hi = __shfl(h1j, i, 64);
            z = fmaf(hi, W2[i * HID + j], z);
        }
        float h2 = fast_tanh(z);
        float v = h2 * W3[j];
#pragma unroll
        for (int off = 32; off; off >>= 1) v += __shfl_xor(v, off, 64);
        if (j == 0) {
            float V = v + b3[0];
            float s, c;
            __sincosf(q2, &s, &c);
            float DEN = 2.0f - c * c;
            float rDEN = __builtin_amdgcn_rcpf(DEN);
            float quad = (p1 * p1 - 2.0f * (c + 1.0f) * p1 * p2 + (2.0f * c + 3.0f) * p2 * p2) * rDEN;
            float kin = 0.5f * quad;
            float s1, c1;
            __sincosf(q1, &s1, &c1);
            float c12 = c1 * c - s1 * s;
            float dq = 1.57079632679489662f - q2;
            float pot = -9.81f * (c12 + 2.0f * c1) + 0.5f * dq * dq;
            edes_out[0] = pot + kin + V;
        }
    }
}

// 8 tanh into fragment F + mask fragment M (wa0..bb1 pre-scaled, in scope)
#define TANH8M(F, M, Q1v, Q2v)                                                                        \
    {                                                                                                 \
        float h;                                                                                      \
        h = fast_tanh2(fmaf(Q1v, wa0.x, fmaf(Q2v, wb0.x, bb0.x))); F[0] = (__bf16)h; M[0] = (__bf16)fmaf(-h, h, 1.0f); \
        h = fast_tanh2(fmaf(Q1v, wa0.y, fmaf(Q2v, wb0.y, bb0.y))); F[1] = (__bf16)h; M[1] = (__bf16)fmaf(-h, h, 1.0f); \
        h = fast_tanh2(fmaf(Q1v, wa0.z, fmaf(Q2v, wb0.z, bb0.z))); F[2] = (__bf16)h; M[2] = (__bf16)fmaf(-h, h, 1.0f); \
        h = fast_tanh2(fmaf(Q1v, wa0.w, fmaf(Q2v, wb0.w, bb0.w))); F[3] = (__bf16)h; M[3] = (__bf16)fmaf(-h, h, 1.0f); \
        h = fast_tanh2(fmaf(Q1v, wa1.x, fmaf(Q2v, wb1.x, bb1.x))); F[4] = (__bf16)h; M[4] = (__bf16)fmaf(-h, h, 1.0f); \
        h = fast_tanh2(fmaf(Q1v, wa1.y, fmaf(Q2v, wb1.y, bb1.y))); F[5] = (__bf16)h; M[5] = (__bf16)fmaf(-h, h, 1.0f); \
        h = fast_tanh2(fmaf(Q1v, wa1.z, fmaf(Q2v, wb1.z, bb1.z))); F[6] = (__bf16)h; M[6] = (__bf16)fmaf(-h, h, 1.0f); \
        h = fast_tanh2(fmaf(Q1v, wa1.w, fmaf(Q2v, wb1.w, bb1.w))); F[7] = (__bf16)h; M[7] = (__bf16)fmaf(-h, h, 1.0f); \
    }

// layer-1 half fragment + mask store for all 4 tiles; scaled weight loads
#define L1HALF4(FA, FB, FC, FD, K0)                                         \
    do {                                                                    \
        const float4 wa0 = *(const float4*)(W1s + (K0));                    \
        const float4 wa1 = *(const float4*)(W1s + (K0) + 4);                \
        const float4 wb0 = *(const float4*)(W1s + HID + (K0));              \
        const float4 wb1 = *(const float4*)(W1s + HID + (K0) + 4);          \
        const float4 bb0 = *(const float4*)(b1s + (K0));                    \
        const float4 bb1 = *(const float4*)(b1s + (K0) + 4);                \
        bf16x8 mA, mB, mC, mD;                                              \
        TANH8M(FA, mA, q1A, q2A)                                            \
        TANH8M(FB, mB, q1B, q2B)                                            \
        TANH8M(FC, mC, q1C, q2C)                                            \
        TANH8M(FD, mD, q1D, q2D)                                            \
        const int mo = rowbase + ((K0) ^ swz);                              \
        *(bf16x8*)(mkA + mo) = mA;                                          \
        *(bf16x8*)(mkB + mo) = mB;                                          \
        *(bf16x8*)(mkC + mo) = mC;                                          \
        *(bf16x8*)(mkD + mo) = mD;                                          \
    } while (0)

#define MFMA __builtin_amdgcn_mfma_f32_16x16x32_bf16

// tanh (arg pre-scaled via GEMM1 tables) + V partial + g2 pack/store (w3v in scope)
#define H2ONE(Z, VP, GBUF, MT)                                                       \
    do {                                                                             \
        float h, g0_, g1_, g2_, g3_;                                                 \
        h = fast_tanh2(Z[0]); VP = fmaf(h, w3v.x, VP); g0_ = w3v.x * (1.0f - h * h); \
        h = fast_tanh2(Z[1]); VP = fmaf(h, w3v.y, VP); g1_ = w3v.y * (1.0f - h * h); \
        h = fast_tanh2(Z[2]); VP = fmaf(h, w3v.z, VP); g2_ = w3v.z * (1.0f - h * h); \
        h = fast_tanh2(Z[3]); VP = fmaf(h, w3v.w, VP); g3_ = w3v.w * (1.0f - h * h); \
        bf16x4 gv = {(__bf16)g0_, (__bf16)g1_, (__bf16)g2_, (__bf16)g3_};            \
        *(bf16x4*)((GBUF) + rowbase + ((16 * (MT) + 4 * hi) ^ swz)) = gv;            \
    } while (0)

// one forward m-tile: scaled bias init + GEMM1(scaled W2T) + tanh/V/g2; accs die here
#define FWDMT(MT)                                                           \
    do {                                                                    \
        const float4 b2v = *(const float4*)(b2s + 16 * (MT) + 4 * hi);      \
        f32x4 zA = {b2v.x, b2v.y, b2v.z, b2v.w};                            \
        f32x4 zB = zA, zC = zA, zD = zA;                                    \
        const bf16x8 wf0 = *(const bf16x8*)(w2t + (MT) * 1024);             \
        zA = MFMA(wf0, a10A, zA, 0, 0, 0);                                  \
        zB = MFMA(wf0, a10B, zB, 0, 0, 0);                                  \
        zC = MFMA(wf0, a10C, zC, 0, 0, 0);                                  \
        zD = MFMA(wf0, a10D, zD, 0, 0, 0);                                  \
        const bf16x8 wf1 = *(const bf16x8*)(w2t + (MT) * 1024 + 32);        \
        zA = MFMA(wf1, a11A, zA, 0, 0, 0);                                  \
        zB = MFMA(wf1, a11B, zB, 0, 0, 0);                                  \
        zC = MFMA(wf1, a11C, zC, 0, 0, 0);                                  \
        zD = MFMA(wf1, a11D, zD, 0, 0, 0);                                  \
        const float4 w3v = *(const float4*)(W3 + 16 * (MT) + 4 * hi);       \
        H2ONE(zA, vpA, g2A, MT);                                            \
        H2ONE(zB, vpB, g2B, MT);                                            \
        H2ONE(zC, vpC, g2C, MT);                                            \
        H2ONE(zD, vpD, g2D, MT);                                            \
    } while (0)

// backward one tile at m-tile MT: mask loaded from LDS (no tanh recompute)
#define DVONE(R, MK, MT, D1, D2)                                                              \
    do {                                                                                      \
        const bf16x4 mv = *(const bf16x4*)((MK) + rowbase + ((16 * (MT) + 4 * hi) ^ swz));    \
        float gi;                                                                             \
        gi = (float)mv[0] * R[0]; D1 = fmaf(w1av.x, gi, D1); D2 = fmaf(w1bv.x, gi, D2);       \
        gi = (float)mv[1] * R[1]; D1 = fmaf(w1av.y, gi, D1); D2 = fmaf(w1bv.y, gi, D2);       \
        gi = (float)mv[2] * R[2]; D1 = fmaf(w1av.z, gi, D1); D2 = fmaf(w1bv.z, gi, D2);       \
        gi = (float)mv[3] * R[3]; D1 = fmaf(w1av.w, gi, D1); D2 = fmaf(w1bv.w, gi, D2);       \
    } while (0)

// one backward m-tile: GEMM2 (raw W2) + mask/dV (raw W1) for all 4 tiles; accs die here
#define BWDMT(MT)                                                           \
    do {                                                                    \
        f32x4 rA = {0.f, 0.f, 0.f, 0.f};                                    \
        f32x4 rB = rA, rC = rA, rD = rA;                                    \
        const bf16x8 wf0 = *(const bf16x8*)(w2b + (MT) * 1024);             \
        rA = MFMA(wf0, a20A, rA, 0, 0, 0);                                  \
        rB = MFMA(wf0, a20B, rB, 0, 0, 0);                                  \
        rC = MFMA(wf0, a20C, rC, 0, 0, 0);                                  \
        rD = MFMA(wf0, a20D, rD, 0, 0, 0);                                  \
        const bf16x8 wf1 = *(const bf16x8*)(w2b + (MT) * 1024 + 32);        \
        rA = MFMA(wf1, a21A, rA, 0, 0, 0);                                  \
        rB = MFMA(wf1, a21B, rB, 0, 0, 0);                                  \
        rC = MFMA(wf1, a21C, rC, 0, 0, 0);                                  \
        rD = MFMA(wf1, a21D, rD, 0, 0, 0);                                  \
        const float4 w1av = *(const float4*)(W1 + 16 * (MT) + 4 * hi);      \
        const float4 w1bv = *(const float4*)(W1 + HID + 16 * (MT) + 4 * hi);\
        DVONE(rA, mkA, MT, d1A, d2A);                                       \
        DVONE(rB, mkB, MT, d1B, d2B);                                       \
        DVONE(rC, mkC, MT, d1C, d2C);                                       \
        DVONE(rD, mkD, MT, d1D, d2D);                                       \
    } while (0)

#define RED2(V) V += __shfl_xor(V, 16, 64); V += __shfl_xor(V, 32, 64);

#define SEL4(A, B, C, D) ((hi == 0) ? (A) : (hi == 1) ? (B) : (hi == 2) ? (C) : (D))

// ---- main: FOUR interleaved 16-row tiles per wave; bf16 masks in LDS; prescaled exp args ----
__global__ __launch_bounds__(256, 2) void pend_kernel(
    const float4* __restrict__ x,
    const float* __restrict__ W1, const float* __restrict__ W1s,
    const float* __restrict__ b1s,
    const __bf16* __restrict__ W2bf, const __bf16* __restrict__ W2Tbf,
    const float* __restrict__ b2s,
    const float* __restrict__ W3, const float* __restrict__ b3,
    const float* __restrict__ Tp, const float* __restrict__ edes_p,
    float4* __restrict__ out, int n)
{
    __shared__ __align__(16) __bf16 lds[4 * 8192];  // per wave: g2 x4 (2KB) + mask x4 (2KB)
    const int tid = threadIdx.x;
    const int w = tid >> 6, l = tid & 63;
    const int lo = l & 15, hi = l >> 4;
    __bf16* g2A = lds + w * 8192;
    __bf16* g2B = g2A + 1024;
    __bf16* g2C = g2B + 1024;
    __bf16* g2D = g2C + 1024;
    __bf16* mkA = g2D + 1024;
    __bf16* mkB = mkA + 1024;
    __bf16* mkC = mkB + 1024;
    __bf16* mkD = mkC + 1024;

    const float E_des = edes_p[0];
    const float Tabs = fabsf(Tp[0]);
    const float b3c = b3[0];

    const int base = blockIdx.x * 256 + w * 64;   // 64 rows per wave
    int eA = base + lo;       if (eA >= n) eA = n - 1;
    int eB = base + 16 + lo;  if (eB >= n) eB = n - 1;
    int eC = base + 32 + lo;  if (eC >= n) eC = n - 1;
    int eD = base + 48 + lo;  if (eD >= n) eD = n - 1;
    const float4 xvA = x[eA];
    const float4 xvB = x[eB];
    const float4 xvC = x[eC];
    const float4 xvD = x[eD];
    const float q1A = xvA.x, q2A = xvA.y, p1A = xvA.z, p2A = xvA.w;
    const float q1B = xvB.x, q2B = xvB.y, p1B = xvB.z, p2B = xvB.w;
    const float q1C = xvC.x, q2C = xvC.y, p1C = xvC.z, p2C = xvC.w;
    const float q1D = xvD.x, q2D = xvD.y, p1D = xvD.z, p2D = xvD.w;

    const int swz = (lo & 7) << 3;          // XOR swizzle on j (bits 3..5)
    const int rowbase = lo * HID;

    // ---- layer-1 for 4 tiles (shared scaled weight loads); masks stored to LDS ----
    bf16x8 a10A, a11A, a10B, a11B, a10C, a11C, a10D, a11D;
    L1HALF4(a10A, a10B, a10C, a10D, 8 * hi);
    L1HALF4(a11A, a11B, a11C, a11D, 32 + 8 * hi);

    const __bf16* w2t = W2Tbf + lo * HID + 8 * hi;   // + mt*1024 (+32 for kh=1)
    const __bf16* w2b = W2bf  + lo * HID + 8 * hi;

    // ---- forward: GEMM1 + h2/V/g2, one m-tile at a time (short acc lifetimes) ----
    float vpA = 0.0f, vpB = 0.0f, vpC = 0.0f, vpD = 0.0f;
    FWDMT(0);
    FWDMT(1);
    FWDMT(2);
    FWDMT(3);

    // ---- GEMM2 A-fragments from LDS (all g2 writes precede these reads, same wave) ----
    const bf16x8 a20A = *(const bf16x8*)(g2A + rowbase + ((8 * hi) ^ swz));
    const bf16x8 a21A = *(const bf16x8*)(g2A + rowbase + ((32 + 8 * hi) ^ swz));
    const bf16x8 a20B = *(const bf16x8*)(g2B + rowbase + ((8 * hi) ^ swz));
    const bf16x8 a21B = *(const bf16x8*)(g2B + rowbase + ((32 + 8 * hi) ^ swz));
    const bf16x8 a20C = *(const bf16x8*)(g2C + rowbase + ((8 * hi) ^ swz));
    const bf16x8 a21C = *(const bf16x8*)(g2C + rowbase + ((32 + 8 * hi) ^ swz));
    const bf16x8 a20D = *(const bf16x8*)(g2D + rowbase + ((8 * hi) ^ swz));
    const bf16x8 a21D = *(const bf16x8*)(g2D + rowbase + ((32 + 8 * hi) ^ swz));

    // ---- backward: GEMM2 + mask/dV, one m-tile at a time ----
    float d1A = 0.f, d2A = 0.f, d1B = 0.f, d2B = 0.f;
    float d1C = 0.f, d2C = 0.f, d1D = 0.f, d2D = 0.f;
    BWDMT(0);
    BWDMT(1);
    BWDMT(2);
    BWDMT(3);

    // ---- reduce over hi-groups; each lane then owns row base + l (tile = hi) ----
    RED2(vpA) RED2(vpB) RED2(vpC) RED2(vpD)
    RED2(d1A) RED2(d1B) RED2(d1C) RED2(d1D)
    RED2(d2A) RED2(d2B) RED2(d2C) RED2(d2D)

    const float V    = SEL4(vpA, vpB, vpC, vpD) + b3c;
    const float dVq1 = SEL4(d1A, d1B, d1C, d1D);
    const float dVq2 = SEL4(d2A, d2B, d2C, d2D);
    const float q1 = SEL4(q1A, q1B, q1C, q1D);
    const float q2 = SEL4(q2A, q2B, q2C, q2D);
    const float p1 = SEL4(p1A, p1B, p1C, p1D);
    const float p2 = SEL4(p2A, p2B, p2C, p2D);

    // ---- physics, once per lane (row = base + l) ----
    float s2q, c2q, s1q, c1q;
    __sincosf(q2, &s2q, &c2q);
    __sincosf(q1, &s1q, &c1q);
    const float s12 = s1q * c2q + c1q * s2q;
    const float c12 = c1q * c2q - s1q * s2q;

    const float cc = c2q, s = s2q;
    const float DEN = 2.0f - cc * cc;        // == 1 + s^2
    const float rDEN = __builtin_amdgcn_rcpf(DEN);
    const float cp1 = cc + 1.0f;

    const float quad = (p1 * p1 - 2.0f * cp1 * p1 * p2 + (2.0f * cc + 3.0f) * p2 * p2) * rDEN;
    const float kin = 0.5f * quad;
    const float dqa = 1.57079632679489662f - q2;
    const float pot = -9.81f * (c12 + 2.0f * c1q) + 0.5f * dqa * dqa;
    const float E = pot + kin + V;

    const float fac = (quad > 0.0f) ? __builtin_amdgcn_rsqf(quad) : 1.0f;
    const float coef = E_des - E;
    const float u1 = -dVq1 + coef * p1 * fac;
    const float u2 = -dVq2 + coef * p2 * fac;

    const float dq1dt = (p1 - cp1 * p2) * rDEN;
    const float dq2dt = ((2.0f * cc + 3.0f) * p2 - cp1 * p1) * rDEN;
    const float dp1dt = -9.81f * (s12 + 2.0f * s1q) + u1;

    const float inner = -p2 * p2 * s * cp1 * (cc + 2.0f)
                + p1 * p2 * s * (fmaf(cc, cc, fmaf(2.0f, cc, 2.0f)))
                - cc * p1 * p1 * s
                + DEN * DEN * (fmaf(9.81f, s12, -0.5f * (3.14159265358979324f - 2.0f * q2)));
    const float dp2dt = -(inner * rDEN * rDEN) + u2;

    const int row = base + l;
    if (row < n) {
        float4 o;
        o.x = Tabs * dq1dt;
        o.y = Tabs * dq2dt;
        o.z = Tabs * dp1dt;
        o.w = Tabs * dp2dt;
        out[row] = o;
    }
}

extern "C" void kernel_launch(void* const* d_in, const int* in_sizes, int n_in,
                              void* d_out, int out_size, void* d_ws, size_t ws_size,
                              hipStream_t stream) {
    const float* x  = (const float*)d_in[0];
    // d_in[1] = t (unused)
    const float* W1 = (const float*)d_in[2];
    const float* b1 = (const float*)d_in[3];
    const float* W2 = (const float*)d_in[4];
    const float* b2 = (const float*)d_in[5];
    const float* W3 = (const float*)d_in[6];
    const float* b3 = (const float*)d_in[7];
    const float* Tp = (const float*)d_in[8];
    const float* x0 = (const float*)d_in[9];

    float* ws = (float*)d_ws;
    float* edes = ws;                                   // 1 float (+ pad to 64 B)
    __bf16* W2bf  = (__bf16*)(ws + 16);                 // 4096 bf16 = 8 KB
    __bf16* W2Tbf = W2bf + HID * HID;                   // 4096 bf16 = 8 KB (scaled by K)
    float* W1s = (float*)(W2Tbf + HID * HID);           // 128 f32 (scaled)
    float* b1s = W1s + 2 * HID;                         // 64 f32 (scaled)
    float* b2s = b1s + HID;                             // 64 f32 (scaled)

    prep_kernel<<<1, 256, 0, stream>>>(W1, b1, W2, b2, W3, b3, x0, edes,
                                       W2bf, W2Tbf, W1s, b1s, b2s);

    int n = in_sizes[0] / 4;  // 500000
    int blocks = (n + 255) / 256;  // 256 rows per block (4 waves x 4 tiles x 16) -> 1954
    pend_kernel<<<blocks, 256, 0, stream>>>((const float4*)x, W1, W1s, b1s,
                                            W2bf, W2Tbf, b2s, W3, b3, Tp, edes,
                                            (float4*)d_out, n);
}